// Round 4
// baseline (26.523 us; speedup 1.0000x reference)
//
#include <hip/hip_runtime.h>

// out[b,p] = sum_s (x[b,s,3] - x[b,S-1,3]) * W[3,p,s] + bias[3,p] + x[b,S-1,3]
// Only channel c=3 of the einsum survives the reference's final [:, :, 3] slice.
//
// Latency-bound fix vs R3: 1024 blocks (4/CU) x 384 threads (6 waves);
// 1 gather load/thread; dot-product split 4-ways per output with shfl reduce.

constexpr int B = 1024, S = 336, C = 321, P = 96;
constexpr int BLOCK = 384;   // 6 waves
constexpr int QCH = S / 4;   // 84 floats = 21 float4 per quarter

__global__ __launch_bounds__(BLOCK, 4) void nlinear_c3_kernel(
    const float* __restrict__ x, const float* __restrict__ W,
    const float* __restrict__ bias, float* __restrict__ out)
{
    __shared__ float xs[S];   // 1.34 KB

    const int b = blockIdx.x;
    const int t = threadIdx.x;

    // Phase 1: gather x[b, :, 3] — one strided, use-once load per thread.
    if (t < S) {
        xs[t] = __builtin_nontemporal_load(&x[((size_t)b * S + t) * C + 3]);
    }
    __syncthreads();

    const int p = t >> 2;     // output index 0..95
    const int q = t & 3;      // s-range quarter

    const float last = xs[S - 1];

    const float4* __restrict__ wp4 =
        reinterpret_cast<const float4*>(W + (size_t)(3 * P + p) * S + q * QCH);
    const float4* __restrict__ xq4 =
        reinterpret_cast<const float4*>(xs + q * QCH);

    float acc = 0.f, sw = 0.f;
    #pragma unroll 7
    for (int i = 0; i < QCH / 4; ++i) {   // 21 float4 MACs
        const float4 w = wp4[i];
        const float4 a = xq4[i];
        acc += a.x * w.x + a.y * w.y + a.z * w.z + a.w * w.w;
        sw  += w.x + w.y + w.z + w.w;
    }

    // Reduce the 4 adjacent lanes holding quarters of output p.
    acc += __shfl_xor(acc, 1);  sw += __shfl_xor(sw, 1);
    acc += __shfl_xor(acc, 2);  sw += __shfl_xor(sw, 2);

    if (q == 0) {
        // (x - last)·w == x·w - last*Σw ; then + bias + last
        out[(size_t)b * P + p] = acc - last * sw + bias[3 * P + p] + last;
    }
}

extern "C" void kernel_launch(void* const* d_in, const int* in_sizes, int n_in,
                              void* d_out, int out_size, void* d_ws, size_t ws_size,
                              hipStream_t stream) {
    const float* x    = (const float*)d_in[0];
    const float* W    = (const float*)d_in[1];
    const float* bias = (const float*)d_in[2];
    float* out        = (float*)d_out;

    nlinear_c3_kernel<<<B, BLOCK, 0, stream>>>(x, W, bias, out);
}

// Round 6
// 22.979 us; speedup vs baseline: 1.1542x; 1.1542x over previous
//
#include <hip/hip_runtime.h>

// out[b,p] = sum_s (x[b,s,3] - x[b,S-1,3]) * W[3,p,s] + bias[3,p] + x[b,S-1,3]
// Only channel c=3 survives the reference's final slice.
//
// R5: split into (1) pure strided gather -> compact ws, (2) dense dot.
// Rationale: R4 showed fusing gather+dot serializes them and multiplies
// W-slice L2 traffic by the block count. Decoupling maximizes gather MLP
// and lets the dot kernel run on dense, cache-hot data.

constexpr int B = 1024, S = 336, C = 321, P = 96;
constexpr int TOTAL = B * S;                 // 344064

// ---- Kernel 1: gather x[:, :, 3] into compact ws[B*S] ----
constexpr int GBLOCK = 256;
constexpr int GELEMS = 2;                    // independent loads per thread
constexpr int GGRID  = TOTAL / (GBLOCK * GELEMS);   // 672 blocks

__global__ __launch_bounds__(GBLOCK) void gather_c3(
    const float* __restrict__ x, float* __restrict__ g)
{
    const int base = blockIdx.x * (GBLOCK * GELEMS) + threadIdx.x;
    // Two independent strided loads in flight per thread.
    const float v0 = x[(size_t)base * C + 3];
    const float v1 = x[(size_t)(base + GBLOCK) * C + 3];
    g[base]          = v0;   // dense coalesced store
    g[base + GBLOCK] = v1;
}

// ---- Kernel 2: out[b,p] = ws[b,:]·W3[p,:] folded with last/bias ----
constexpr int CBLOCK = 192;                  // 2 groups of 96; 3 waves
constexpr int BPB    = 4;                    // batches per block
constexpr int CGRID  = B / BPB;              // 256 blocks

__global__ __launch_bounds__(CBLOCK) void dot_c3(
    const float* __restrict__ g, const float* __restrict__ W,
    const float* __restrict__ bias, float* __restrict__ out)
{
    const int t   = threadIdx.x;
    const int grp = t / 96;                  // 0 or 1
    const int p   = t - grp * 96;            // output index 0..95
    const int bA  = blockIdx.x * BPB + 2 * grp;
    const int bB  = bA + 1;

    // W3 row p: 336 floats = 1344 B, 16B-aligned.
    const float4* __restrict__ wp4 =
        reinterpret_cast<const float4*>(W + (size_t)(3 * P + p) * S);
    const float4* __restrict__ xA4 =
        reinterpret_cast<const float4*>(g + (size_t)bA * S);
    const float4* __restrict__ xB4 =
        reinterpret_cast<const float4*>(g + (size_t)bB * S);

    float accA = 0.f, accB = 0.f, sw = 0.f;
    #pragma unroll 4
    for (int i = 0; i < S / 4; ++i) {        // 84 float4 MACs, W shared by 2 batches
        const float4 w = wp4[i];
        const float4 a = xA4[i];
        const float4 c = xB4[i];
        accA += a.x * w.x + a.y * w.y + a.z * w.z + a.w * w.w;
        accB += c.x * w.x + c.y * w.y + c.z * w.z + c.w * w.w;
        sw   += w.x + w.y + w.z + w.w;
    }

    const float lastA = g[(size_t)bA * S + (S - 1)];
    const float lastB = g[(size_t)bB * S + (S - 1)];
    const float bb    = bias[3 * P + p];
    // (x - last)·w == x·w - last*Σw ; then + bias + last
    out[(size_t)bA * P + p] = accA - lastA * sw + bb + lastA;
    out[(size_t)bB * P + p] = accB - lastB * sw + bb + lastB;
}

extern "C" void kernel_launch(void* const* d_in, const int* in_sizes, int n_in,
                              void* d_out, int out_size, void* d_ws, size_t ws_size,
                              hipStream_t stream) {
    const float* x    = (const float*)d_in[0];
    const float* W    = (const float*)d_in[1];
    const float* bias = (const float*)d_in[2];
    float* out        = (float*)d_out;
    float* g          = (float*)d_ws;        // needs B*S*4 = 1.38 MB scratch

    gather_c3<<<GGRID, GBLOCK, 0, stream>>>(x, g);
    dot_c3<<<CGRID, CBLOCK, 0, stream>>>(g, W, bias, out);
}

// Round 7
// 19.738 us; speedup vs baseline: 1.3437x; 1.1642x over previous
//
#include <hip/hip_runtime.h>

// out[b,p] = sum_s (x[b,s,3] - x[b,S-1,3]) * W[3,p,s] + bias[3,p] + x[b,S-1,3]
// Only channel c=3 survives the reference's final slice.
//
// R7: the strided gather (344k distinct 64B lines, 1 per ~1.3KB) is
// DRAM-activation-bound at ~1.2 TB/s effective => ~18-19 us hard floor
// (measured via the R6 split). Strategy: single fused launch, 2 blocks/CU
// so compute overlaps other blocks' gathers, minimal tail.

constexpr int B = 1024, S = 336, C = 321, P = 96;
constexpr int BPB   = 2;     // batches per block
constexpr int BLOCK = 256;   // 4 waves
constexpr int GRID  = B / BPB;   // 512 blocks = 2 per CU

__global__ __launch_bounds__(BLOCK) void nlinear_c3_fused(
    const float* __restrict__ x, const float* __restrict__ W,
    const float* __restrict__ bias, float* __restrict__ out)
{
    __shared__ float xs[BPB][S];   // 2.6 KB

    const int t  = threadIdx.x;
    const int b0 = blockIdx.x * BPB;

    // ---- Phase 1: gather 672 strided elements with 3 back-to-back loads ----
    const size_t xbase = (size_t)b0 * S * C + 3;
    const int i0 = t, i1 = t + BLOCK, i2 = t + 2 * BLOCK;
    const float v0 = x[xbase + (size_t)i0 * C];
    const float v1 = x[xbase + (size_t)i1 * C];
    float v2 = 0.f;
    if (i2 < BPB * S) v2 = x[xbase + (size_t)i2 * C];

    ((float*)xs)[i0] = v0;
    ((float*)xs)[i1] = v1;
    if (i2 < BPB * S) ((float*)xs)[i2] = v2;
    __syncthreads();

    // ---- Phase 2: 192 threads: group g (0/1) handles batch b0+g, thread p ----
    if (t < 2 * 96) {
        const int g = t / 96;
        const int p = t - g * 96;
        const int b = b0 + g;

        const float last = xs[g][S - 1];

        const float4* __restrict__ wp4 =
            reinterpret_cast<const float4*>(W + (size_t)(3 * P + p) * S);  // 1344B row
        const float4* __restrict__ xg4 = reinterpret_cast<const float4*>(xs[g]);

        float acc = 0.f, sw = 0.f;
        #pragma unroll 4
        for (int i = 0; i < S / 4; ++i) {   // 84 float4 MACs
            const float4 w = wp4[i];
            const float4 a = xg4[i];
            acc += a.x * w.x + a.y * w.y + a.z * w.z + a.w * w.w;
            sw  += w.x + w.y + w.z + w.w;
        }

        // (x - last)·w == x·w - last*Σw ; then + bias + last
        out[(size_t)b * P + p] = acc - last * sw + bias[3 * P + p] + last;
    }
}

extern "C" void kernel_launch(void* const* d_in, const int* in_sizes, int n_in,
                              void* d_out, int out_size, void* d_ws, size_t ws_size,
                              hipStream_t stream) {
    const float* x    = (const float*)d_in[0];
    const float* W    = (const float*)d_in[1];
    const float* bias = (const float*)d_in[2];
    float* out        = (float*)d_out;

    nlinear_c3_fused<<<GRID, BLOCK, 0, stream>>>(x, W, bias, out);
}